// Round 25
// baseline (63.276 us; speedup 1.0000x reference)
//
#include <hip/hip_runtime.h>

typedef __attribute__((ext_vector_type(8)))  short short8;
typedef __attribute__((ext_vector_type(16))) float f32x16;
typedef __attribute__((ext_vector_type(16))) unsigned u32x16;

#define NPTS 2048
#define BATCH 32
#define NUM_CLASSES 6
#define THREADS 512
#define REPEAT 8   // DIAGNOSTIC: pipelined loop x8 (idempotent min re-fold)
// grid = 2 dirs * 32 batches * 4 qchunks(512) = 256 blocks (1 block/CU)
#define BF16_ONE ((short)0x3F80)
#define FMAX_BITS 0x7F7FFFFFu

__device__ __forceinline__ unsigned short f2bf(float x) {
    union { float f; unsigned u; } v; v.f = x;
    unsigned r = v.u + 0x7FFF + ((v.u >> 16) & 1);   // RNE to bf16
    return (unsigned short)(r >> 16);
}
__device__ __forceinline__ float bf2f(unsigned short h) {
    union { unsigned u; float f; } v; v.u = ((unsigned)h) << 16; return v.f;
}
__device__ __forceinline__ unsigned f2u(float x) {
    union { float f; unsigned u; } v; v.f = x; return v.u;
}
__device__ __forceinline__ float u2f(unsigned x) {
    union { unsigned u; float f; } v; v.u = x; return v.f;
}
// Distances strictly positive -> uint order == float order (R15-verified).
__device__ __forceinline__ unsigned umin2(unsigned a, unsigned b) {
    return a < b ? a : b;
}
template<int CTRL>
__device__ __forceinline__ unsigned dpp_ror_umin(unsigned v) {
    unsigned r = (unsigned)__builtin_amdgcn_update_dpp((int)v, (int)v, CTRL, 0xF, 0xF, false);
    return umin2(v, r);
}
__device__ __forceinline__ unsigned swz16_umin(unsigned v) {
    unsigned r = (unsigned)__builtin_amdgcn_ds_swizzle((int)v, 0x401F);  // lane^16
    return umin2(v, r);
}

// K-slot plan (K=16), D = a2 + b2 - 2 a.b (absmax-0 verified R3-R24):
//  k0-2: A=ah B=-2bh | k3-5: A=al B=-2bh | k6-8: A=ah B=-2bl
//  k9: A=1 B=b2h | k10: A=1 B=b2l | k11: A=a2h B=1 | k12: A=a2l B=1 | k13-15: 0
// LDS: per 32-cand tile, 1024 B = [32 x kg0][32 x kg1], conflict-free (R13).
// __launch_bounds__(512,2): 8 waves/block, 1 block/CU, 2 waves/SIMD at the
// 256-VGPR budget (R15 register mode). 2-deep pipeline (R18). DPP epilogue
// (R19). R25: REPEAT=8 diagnostic to split loop(L) vs fixed(F) post-R15 and
// surface this kernel's counters above the 39us harness poison-fills.
__global__ __launch_bounds__(THREADS, 2) void chamfer_mfma32(
    const float* __restrict__ inst, const float* __restrict__ model,
    float* __restrict__ partial)
{
    __shared__ char  cands[NPTS * 32];   // 64 KB
    __shared__ float wsum[8];

    const int blk   = blockIdx.x;
    const int dir   = blk >> 7;
    const int batch = (blk >> 2) & 31;
    const int qc    = blk & 3;
    const int tid   = threadIdx.x;
    const int lane  = tid & 63, wid = tid >> 6;     // wid 0..7
    const int lh    = lane >> 5, lr = lane & 31;

    const float* __restrict__ Q = dir ? model : inst;
    const float* __restrict__ C = dir ? inst  : model;

    // ---- stage candidates into tiled B-frag layout (4 cands/thread) ----
    const float* cb = C + (size_t)batch * NPTS * 3;
    for (int c = tid; c < NPTS; c += THREADS) {
        float bx = cb[c*3+0], by = cb[c*3+1], bz = cb[c*3+2];
        float m2x = -2.f*bx, m2y = -2.f*by, m2z = -2.f*bz;
        unsigned short hx = f2bf(m2x), hy = f2bf(m2y), hz = f2bf(m2z);
        unsigned short lx = f2bf(m2x - bf2f(hx));
        unsigned short ly = f2bf(m2y - bf2f(hy));
        unsigned short lz = f2bf(m2z - bf2f(hz));
        float b2 = fmaf(bx,bx, fmaf(by,by, bz*bz));
        unsigned short b2h = f2bf(b2);
        unsigned short b2l = f2bf(b2 - bf2f(b2h));
        short8 kg0 = { (short)hx,(short)hy,(short)hz,(short)hx,(short)hy,(short)hz,(short)lx,(short)ly };
        short8 kg1 = { (short)lz,(short)b2h,(short)b2l, BF16_ONE, BF16_ONE, 0,0,0 };
        char* tbase = cands + (c >> 5) * 1024 + (c & 31) * 16;
        *(short8*)(tbase)       = kg0;
        *(short8*)(tbase + 512) = kg1;
    }

    // ---- A-frags from global (row = lane&31, k = (lane>>5)*8 + j) ----
    short8 af0, af1;
    const float* qb = Q + ((size_t)batch * NPTS + (size_t)qc * 512) * 3;
    #pragma unroll
    for (int qt = 0; qt < 2; ++qt) {
        const int qi = (wid * 2 + qt) * 32 + lr;    // 0..511
        float x = qb[qi*3+0], y = qb[qi*3+1], z = qb[qi*3+2];
        unsigned short hx = f2bf(x), hy = f2bf(y), hz = f2bf(z);
        unsigned short lx = f2bf(x - bf2f(hx));
        unsigned short ly = f2bf(y - bf2f(hy));
        unsigned short lz = f2bf(z - bf2f(hz));
        float a2 = fmaf(x,x, fmaf(y,y, z*z));
        unsigned short a2h = f2bf(a2);
        unsigned short a2l = f2bf(a2 - bf2f(a2h));
        short8 f;
        if (lh == 0)
            f = (short8){ (short)hx,(short)hy,(short)hz,(short)lx,(short)ly,(short)lz,(short)hx,(short)hy };
        else
            f = (short8){ (short)hz, BF16_ONE, BF16_ONE, (short)a2h,(short)a2l, 0,0,0 };
        if (qt == 0) af0 = f; else af1 = f;
    }
    __syncthreads();

    // ---- software-pipelined main loop x REPEAT (R18-verified structure) ----
    u32x16 mnU, mnU2;
    f32x16 zero16;
    #pragma unroll
    for (int r = 0; r < 16; ++r) { mnU[r] = FMAX_BITS; mnU2[r] = FMAX_BITS; zero16[r] = 0.f; }

    #pragma unroll 1
    for (int rep = 0; rep < REPEAT; ++rep) {
        asm volatile("" ::: "memory");   // block cross-rep CSE; LDS unchanged
        const char* cp = cands + lh * 512 + lr * 16;
        short8 c0 = *(const short8*)(cp);
        short8 c1 = *(const short8*)(cp + 1024);
        short8 n0 = *(const short8*)(cp + 2048);
        short8 n1 = *(const short8*)(cp + 3072);
        cp += 4096;
        f32x16 p00 = __builtin_amdgcn_mfma_f32_32x32x16_bf16(af0, c0, zero16, 0,0,0);
        f32x16 p01 = __builtin_amdgcn_mfma_f32_32x32x16_bf16(af0, c1, zero16, 0,0,0);
        f32x16 p10 = __builtin_amdgcn_mfma_f32_32x32x16_bf16(af1, c0, zero16, 0,0,0);
        f32x16 p11 = __builtin_amdgcn_mfma_f32_32x32x16_bf16(af1, c1, zero16, 0,0,0);

        #pragma unroll 2
        for (int s = 1; s < 31; ++s) {        // stages 1..30 (tiles 2..61)
            c0 = n0; c1 = n1;
            n0 = *(const short8*)(cp);        // prefetch stage s+1
            n1 = *(const short8*)(cp + 1024);
            cp += 2048;
            f32x16 q00 = __builtin_amdgcn_mfma_f32_32x32x16_bf16(af0, c0, zero16, 0,0,0);
            f32x16 q01 = __builtin_amdgcn_mfma_f32_32x32x16_bf16(af0, c1, zero16, 0,0,0);
            f32x16 q10 = __builtin_amdgcn_mfma_f32_32x32x16_bf16(af1, c0, zero16, 0,0,0);
            f32x16 q11 = __builtin_amdgcn_mfma_f32_32x32x16_bf16(af1, c1, zero16, 0,0,0);
            #pragma unroll
            for (int r = 0; r < 16; ++r)      // fold stage s-1 (completed)
                mnU[r]  = umin2(umin2(f2u(p00[r]), f2u(p01[r])), mnU[r]);
            #pragma unroll
            for (int r = 0; r < 16; ++r)
                mnU2[r] = umin2(umin2(f2u(p10[r]), f2u(p11[r])), mnU2[r]);
            p00 = q00; p01 = q01; p10 = q10; p11 = q11;
        }
        {   // stage 31 (tiles 62,63, prefetched in n0/n1) + drain folds
            f32x16 q00 = __builtin_amdgcn_mfma_f32_32x32x16_bf16(af0, n0, zero16, 0,0,0);
            f32x16 q01 = __builtin_amdgcn_mfma_f32_32x32x16_bf16(af0, n1, zero16, 0,0,0);
            f32x16 q10 = __builtin_amdgcn_mfma_f32_32x32x16_bf16(af1, n0, zero16, 0,0,0);
            f32x16 q11 = __builtin_amdgcn_mfma_f32_32x32x16_bf16(af1, n1, zero16, 0,0,0);
            #pragma unroll
            for (int r = 0; r < 16; ++r) {
                mnU[r]  = umin2(umin2(f2u(p00[r]), f2u(p01[r])), mnU[r]);
                mnU2[r] = umin2(umin2(f2u(p10[r]), f2u(p11[r])), mnU2[r]);
            }
            #pragma unroll
            for (int r = 0; r < 16; ++r) {
                mnU[r]  = umin2(umin2(f2u(q00[r]), f2u(q01[r])), mnU[r]);
                mnU2[r] = umin2(umin2(f2u(q10[r]), f2u(q11[r])), mnU2[r]);
            }
        }
    }

    // ---- epilogue: DPP row_ror col-reduce (R19-verified) ----
    float s = 0.f;
    #pragma unroll
    for (int r = 0; r < 16; ++r) {
        unsigned v = mnU[r];
        v = dpp_ror_umin<0x121>(v);
        v = dpp_ror_umin<0x122>(v);
        v = dpp_ror_umin<0x124>(v);
        v = dpp_ror_umin<0x128>(v);
        v = swz16_umin(v);
        s += u2f(v);
        unsigned w = mnU2[r];
        w = dpp_ror_umin<0x121>(w);
        w = dpp_ror_umin<0x122>(w);
        w = dpp_ror_umin<0x124>(w);
        w = dpp_ror_umin<0x128>(w);
        w = swz16_umin(w);
        s += u2f(w);
    }
    s += __shfl_xor(s, 32, 64);      // combine lh=0 / lh=1 query halves
    if (lane == 0) wsum[wid] = s;
    __syncthreads();
    if (tid == 0) {
        partial[blk] = ((wsum[0] + wsum[1]) + (wsum[2] + wsum[3]))
                     + ((wsum[4] + wsum[5]) + (wsum[6] + wsum[7]));
    }
}

__global__ __launch_bounds__(256) void finalize_kernel(
    const float* __restrict__ partial, const float* __restrict__ pred,
    const int* __restrict__ gt, float* __restrict__ out)
{
    __shared__ float s_ce[BATCH];
    __shared__ float wsum[4];
    const int tid = threadIdx.x;

    float v = partial[tid];          // 256 partials
    #pragma unroll
    for (int o = 32; o > 0; o >>= 1) v += __shfl_down(v, o, 64);
    const int lane = tid & 63, wid = tid >> 6;
    if (lane == 0) wsum[wid] = v;

    if (tid < BATCH) {
        const float* row = pred + tid * NUM_CLASSES;
        float mx = row[0];
        #pragma unroll
        for (int c = 1; c < NUM_CLASSES; ++c) mx = fmaxf(mx, row[c]);
        float se = 0.f;
        #pragma unroll
        for (int c = 0; c < NUM_CLASSES; ++c) se += __expf(row[c] - mx);
        const int lbl = gt[tid];
        s_ce[tid] = -(row[lbl] - mx - __logf(se));
    }
    __syncthreads();

    if (tid == 0) {
        float cd_sum = (wsum[0] + wsum[1]) + (wsum[2] + wsum[3]);
        float cd = cd_sum / (float)(BATCH * NPTS);
        float ce = 0.f;
        for (int i = 0; i < BATCH; ++i) ce += s_ce[i];
        ce /= (float)BATCH;
        out[0] = 5.f * cd + ce;
        out[1] = cd;
        out[2] = ce;
    }
}

extern "C" void kernel_launch(void* const* d_in, const int* in_sizes, int n_in,
                              void* d_out, int out_size, void* d_ws, size_t ws_size,
                              hipStream_t stream) {
    const float* inst  = (const float*)d_in[0];
    const float* model = (const float*)d_in[1];
    const float* pred  = (const float*)d_in[2];
    const int*   gt    = (const int*)d_in[3];
    float* out     = (float*)d_out;
    float* partial = (float*)d_ws;   // 256 floats

    chamfer_mfma32<<<256, THREADS, 0, stream>>>(inst, model, partial);
    finalize_kernel<<<1, 256, 0, stream>>>(partial, pred, gt, out);
}

// Round 26
// 17.338 us; speedup vs baseline: 3.6496x; 3.6496x over previous
//
#include <hip/hip_runtime.h>

typedef __attribute__((ext_vector_type(8)))  short short8;
typedef __attribute__((ext_vector_type(16))) float f32x16;
typedef __attribute__((ext_vector_type(16))) unsigned u32x16;

#define NPTS 2048
#define BATCH 32
#define NUM_CLASSES 6
#define THREADS 512
// grid = 2 dirs * 32 batches * 8 qchunks(256) = 512 blocks (2 blocks/CU)
#define BF16_ONE ((short)0x3F80)
#define FMAX_BITS 0x7F7FFFFFu

__device__ __forceinline__ unsigned short f2bf(float x) {
    union { float f; unsigned u; } v; v.f = x;
    unsigned r = v.u + 0x7FFF + ((v.u >> 16) & 1);   // RNE to bf16
    return (unsigned short)(r >> 16);
}
__device__ __forceinline__ float bf2f(unsigned short h) {
    union { unsigned u; float f; } v; v.u = ((unsigned)h) << 16; return v.f;
}
__device__ __forceinline__ unsigned f2u(float x) {
    union { float f; unsigned u; } v; v.f = x; return v.u;
}
__device__ __forceinline__ float u2f(unsigned x) {
    union { unsigned u; float f; } v; v.u = x; return v.f;
}
// Distances strictly positive -> uint order == float order (R15-verified).
__device__ __forceinline__ unsigned umin2(unsigned a, unsigned b) {
    return a < b ? a : b;
}
template<int CTRL>
__device__ __forceinline__ unsigned dpp_ror_umin(unsigned v) {
    unsigned r = (unsigned)__builtin_amdgcn_update_dpp((int)v, (int)v, CTRL, 0xF, 0xF, false);
    return umin2(v, r);
}
__device__ __forceinline__ unsigned swz16_umin(unsigned v) {
    unsigned r = (unsigned)__builtin_amdgcn_ds_swizzle((int)v, 0x401F);  // lane^16
    return umin2(v, r);
}

// K-slot plan (K=16), D = a2 + b2 - 2 a.b (absmax-0 verified R3-R25):
//  k0-2: A=ah B=-2bh | k3-5: A=al B=-2bh | k6-8: A=ah B=-2bl
//  k9: A=1 B=b2h | k10: A=1 B=b2l | k11: A=a2h B=1 | k12: A=a2l B=1 | k13-15: 0
// LDS: per 32-cand tile, 1024 B = [32 x kg0][32 x kg1], conflict-free (R13).
//
// R26: 4 waves/SIMD with a 128-VGPR-safe live set. R25 measured the loop at
// SERIAL pipe-sum (DS 2.56 + VALU-fold 3.4 + matrix 0.85 us, VALUBusy 55%) --
// 2 lockstep waves/SIMD give zero cross-pipe overlap, and F=10.6us of
// staging/input latency is unhidden. This round: 512-thr blocks, grid 512
// (2 blocks/CU via 64KB LDS), __launch_bounds__(512,4) -> 128-VGPR budget,
// ONE A-frag per wave (32 queries, 2 MFMA/stage) so peak live ~110 regs fits
// the budget WITHOUT the R13/R16 AGPR-copy mode. Waves drift (no in-loop
// barriers) -> DS/VALU/matrix overlap across 4 waves/SIMD (m114).
__global__ __launch_bounds__(THREADS, 4) void chamfer_mfma32(
    const float* __restrict__ inst, const float* __restrict__ model,
    float* __restrict__ partial)
{
    __shared__ char  cands[NPTS * 32];   // 64 KB
    __shared__ float wsum[8];

    const int blk   = blockIdx.x;
    const int dir   = blk >> 8;
    const int batch = (blk >> 3) & 31;
    const int qc    = blk & 7;
    const int tid   = threadIdx.x;
    const int lane  = tid & 63, wid = tid >> 6;     // wid 0..7
    const int lh    = lane >> 5, lr = lane & 31;

    const float* __restrict__ Q = dir ? model : inst;
    const float* __restrict__ C = dir ? inst  : model;

    // ---- stage candidates into tiled B-frag layout (4 cands/thread) ----
    const float* cb = C + (size_t)batch * NPTS * 3;
    for (int c = tid; c < NPTS; c += THREADS) {
        float bx = cb[c*3+0], by = cb[c*3+1], bz = cb[c*3+2];
        float m2x = -2.f*bx, m2y = -2.f*by, m2z = -2.f*bz;
        unsigned short hx = f2bf(m2x), hy = f2bf(m2y), hz = f2bf(m2z);
        unsigned short lx = f2bf(m2x - bf2f(hx));
        unsigned short ly = f2bf(m2y - bf2f(hy));
        unsigned short lz = f2bf(m2z - bf2f(hz));
        float b2 = fmaf(bx,bx, fmaf(by,by, bz*bz));
        unsigned short b2h = f2bf(b2);
        unsigned short b2l = f2bf(b2 - bf2f(b2h));
        short8 kg0 = { (short)hx,(short)hy,(short)hz,(short)hx,(short)hy,(short)hz,(short)lx,(short)ly };
        short8 kg1 = { (short)lz,(short)b2h,(short)b2l, BF16_ONE, BF16_ONE, 0,0,0 };
        char* tbase = cands + (c >> 5) * 1024 + (c & 31) * 16;
        *(short8*)(tbase)       = kg0;
        *(short8*)(tbase + 512) = kg1;
    }

    // ---- ONE A-frag per wave: 32 queries (row = lane&31, k = (lane>>5)*8+j) ----
    short8 af;
    {
        const float* qb = Q + ((size_t)batch * NPTS + (size_t)qc * 256) * 3;
        const int qi = wid * 32 + lr;               // 0..255
        float x = qb[qi*3+0], y = qb[qi*3+1], z = qb[qi*3+2];
        unsigned short hx = f2bf(x), hy = f2bf(y), hz = f2bf(z);
        unsigned short lx = f2bf(x - bf2f(hx));
        unsigned short ly = f2bf(y - bf2f(hy));
        unsigned short lz = f2bf(z - bf2f(hz));
        float a2 = fmaf(x,x, fmaf(y,y, z*z));
        unsigned short a2h = f2bf(a2);
        unsigned short a2l = f2bf(a2 - bf2f(a2h));
        if (lh == 0)
            af = (short8){ (short)hx,(short)hy,(short)hz,(short)lx,(short)ly,(short)lz,(short)hx,(short)hy };
        else
            af = (short8){ (short)hz, BF16_ONE, BF16_ONE, (short)a2h,(short)a2l, 0,0,0 };
    }
    __syncthreads();

    // ---- 2-deep pipelined loop: 32 stages x 2 tiles, 2 MFMA/stage ----
    u32x16 mnU;
    f32x16 zero16;
    #pragma unroll
    for (int r = 0; r < 16; ++r) { mnU[r] = FMAX_BITS; zero16[r] = 0.f; }

    const char* cp = cands + lh * 512 + lr * 16;
    short8 c0 = *(const short8*)(cp);
    short8 c1 = *(const short8*)(cp + 1024);
    short8 n0 = *(const short8*)(cp + 2048);
    short8 n1 = *(const short8*)(cp + 3072);
    cp += 4096;
    f32x16 p0 = __builtin_amdgcn_mfma_f32_32x32x16_bf16(af, c0, zero16, 0,0,0);
    f32x16 p1 = __builtin_amdgcn_mfma_f32_32x32x16_bf16(af, c1, zero16, 0,0,0);

    #pragma unroll 2
    for (int s = 1; s < 31; ++s) {        // stages 1..30 (tiles 2..61)
        c0 = n0; c1 = n1;
        n0 = *(const short8*)(cp);        // prefetch stage s+1
        n1 = *(const short8*)(cp + 1024);
        cp += 2048;
        f32x16 q0 = __builtin_amdgcn_mfma_f32_32x32x16_bf16(af, c0, zero16, 0,0,0);
        f32x16 q1 = __builtin_amdgcn_mfma_f32_32x32x16_bf16(af, c1, zero16, 0,0,0);
        #pragma unroll
        for (int r = 0; r < 16; ++r)      // fold stage s-1 (completed)
            mnU[r] = umin2(umin2(f2u(p0[r]), f2u(p1[r])), mnU[r]);
        p0 = q0; p1 = q1;
    }
    {   // stage 31 (tiles 62,63, prefetched in n0/n1) + drain folds
        f32x16 q0 = __builtin_amdgcn_mfma_f32_32x32x16_bf16(af, n0, zero16, 0,0,0);
        f32x16 q1 = __builtin_amdgcn_mfma_f32_32x32x16_bf16(af, n1, zero16, 0,0,0);
        #pragma unroll
        for (int r = 0; r < 16; ++r)
            mnU[r] = umin2(umin2(f2u(p0[r]), f2u(p1[r])), mnU[r]);
        #pragma unroll
        for (int r = 0; r < 16; ++r)
            mnU[r] = umin2(umin2(f2u(q0[r]), f2u(q1[r])), mnU[r]);
    }

    // ---- epilogue: DPP row_ror col-reduce (R19-verified) ----
    float s = 0.f;
    #pragma unroll
    for (int r = 0; r < 16; ++r) {
        unsigned v = mnU[r];
        v = dpp_ror_umin<0x121>(v);
        v = dpp_ror_umin<0x122>(v);
        v = dpp_ror_umin<0x124>(v);
        v = dpp_ror_umin<0x128>(v);
        v = swz16_umin(v);
        s += u2f(v);
    }
    s += __shfl_xor(s, 32, 64);      // combine lh=0 / lh=1 row halves
    if (lane == 0) wsum[wid] = s;
    __syncthreads();
    if (tid == 0) {
        partial[blk] = ((wsum[0] + wsum[1]) + (wsum[2] + wsum[3]))
                     + ((wsum[4] + wsum[5]) + (wsum[6] + wsum[7]));
    }
}

__global__ __launch_bounds__(256) void finalize_kernel(
    const float* __restrict__ partial, const float* __restrict__ pred,
    const int* __restrict__ gt, float* __restrict__ out)
{
    __shared__ float s_ce[BATCH];
    __shared__ float wsum[4];
    const int tid = threadIdx.x;

    float v = partial[tid] + partial[tid + 256];   // 512 partials
    #pragma unroll
    for (int o = 32; o > 0; o >>= 1) v += __shfl_down(v, o, 64);
    const int lane = tid & 63, wid = tid >> 6;
    if (lane == 0) wsum[wid] = v;

    if (tid < BATCH) {
        const float* row = pred + tid * NUM_CLASSES;
        float mx = row[0];
        #pragma unroll
        for (int c = 1; c < NUM_CLASSES; ++c) mx = fmaxf(mx, row[c]);
        float se = 0.f;
        #pragma unroll
        for (int c = 0; c < NUM_CLASSES; ++c) se += __expf(row[c] - mx);
        const int lbl = gt[tid];
        s_ce[tid] = -(row[lbl] - mx - __logf(se));
    }
    __syncthreads();

    if (tid == 0) {
        float cd_sum = (wsum[0] + wsum[1]) + (wsum[2] + wsum[3]);
        float cd = cd_sum / (float)(BATCH * NPTS);
        float ce = 0.f;
        for (int i = 0; i < BATCH; ++i) ce += s_ce[i];
        ce /= (float)BATCH;
        out[0] = 5.f * cd + ce;
        out[1] = cd;
        out[2] = ce;
    }
}

extern "C" void kernel_launch(void* const* d_in, const int* in_sizes, int n_in,
                              void* d_out, int out_size, void* d_ws, size_t ws_size,
                              hipStream_t stream) {
    const float* inst  = (const float*)d_in[0];
    const float* model = (const float*)d_in[1];
    const float* pred  = (const float*)d_in[2];
    const int*   gt    = (const int*)d_in[3];
    float* out     = (float*)d_out;
    float* partial = (float*)d_ws;   // 512 floats

    chamfer_mfma32<<<512, THREADS, 0, stream>>>(inst, model, partial);
    finalize_kernel<<<1, 256, 0, stream>>>(partial, pred, gt, out);
}

// Round 27
// 17.132 us; speedup vs baseline: 3.6934x; 1.0120x over previous
//
#include <hip/hip_runtime.h>

typedef __attribute__((ext_vector_type(8)))  short short8;
typedef __attribute__((ext_vector_type(16))) float f32x16;
typedef __attribute__((ext_vector_type(16))) unsigned u32x16;

#define NPTS 2048
#define BATCH 32
#define NUM_CLASSES 6
#define THREADS 512
// grid = 2 dirs * 32 batches * 4 qchunks(512) = 256 blocks (1 block/CU)
#define BF16_ONE ((short)0x3F80)
#define FMAX_BITS 0x7F7FFFFFu

__device__ __forceinline__ unsigned short f2bf(float x) {
    union { float f; unsigned u; } v; v.f = x;
    unsigned r = v.u + 0x7FFF + ((v.u >> 16) & 1);   // RNE to bf16
    return (unsigned short)(r >> 16);
}
__device__ __forceinline__ float bf2f(unsigned short h) {
    union { unsigned u; float f; } v; v.u = ((unsigned)h) << 16; return v.f;
}
__device__ __forceinline__ unsigned f2u(float x) {
    union { float f; unsigned u; } v; v.f = x; return v.u;
}
__device__ __forceinline__ float u2f(unsigned x) {
    union { unsigned u; float f; } v; v.u = x; return v.f;
}
// Distances strictly positive -> uint order == float order (R15-verified).
__device__ __forceinline__ unsigned umin2(unsigned a, unsigned b) {
    return a < b ? a : b;
}
template<int CTRL>
__device__ __forceinline__ unsigned dpp_ror_umin(unsigned v) {
    unsigned r = (unsigned)__builtin_amdgcn_update_dpp((int)v, (int)v, CTRL, 0xF, 0xF, false);
    return umin2(v, r);
}
__device__ __forceinline__ unsigned swz16_umin(unsigned v) {
    unsigned r = (unsigned)__builtin_amdgcn_ds_swizzle((int)v, 0x401F);  // lane^16
    return umin2(v, r);
}

// K-slot plan (K=16), D = a2 + b2 - 2 a.b (absmax-0 verified R3-R26):
//  k0-2: A=ah B=-2bh | k3-5: A=al B=-2bh | k6-8: A=ah B=-2bl
//  k9: A=1 B=b2h | k10: A=1 B=b2l | k11: A=a2h B=1 | k12: A=a2l B=1 | k13-15: 0
// LDS: per 32-cand tile, 1024 B = [32 x kg0][32 x kg1], conflict-free (R13).
// __launch_bounds__(512,2): 8 waves/block, 1 block/CU, 2 waves/SIMD (R15
// register mode). 2-deep pipeline (R18). DPP epilogue (R19). R27: staging
// loads vectorized (G13) -- each thread owns 4 CONSECUTIVE cands = 48 B =
// 3x dwordx4 instead of 12 scalar dwords (4x fewer VMEM issues in the cold
// phase). Conversion and LDS layout unchanged.
__global__ __launch_bounds__(THREADS, 2) void chamfer_mfma32(
    const float* __restrict__ inst, const float* __restrict__ model,
    float* __restrict__ partial)
{
    __shared__ char  cands[NPTS * 32];   // 64 KB
    __shared__ float wsum[8];

    const int blk   = blockIdx.x;
    const int dir   = blk >> 7;
    const int batch = (blk >> 2) & 31;
    const int qc    = blk & 3;
    const int tid   = threadIdx.x;
    const int lane  = tid & 63, wid = tid >> 6;     // wid 0..7
    const int lh    = lane >> 5, lr = lane & 31;

    const float* __restrict__ Q = dir ? model : inst;
    const float* __restrict__ C = dir ? inst  : model;

    // ---- stage candidates: 4 consecutive cands/thread via 3x dwordx4 ----
    {
        const int c0i = tid * 4;
        const float4* src = (const float4*)(C + (size_t)batch * NPTS * 3 + (size_t)c0i * 3);
        float4 f0 = src[0];   // b0x b0y b0z b1x
        float4 f1 = src[1];   // b1y b1z b2x b2y
        float4 f2 = src[2];   // b2z b3x b3y b3z
        float bxs[4] = { f0.x, f0.w, f1.z, f2.y };
        float bys[4] = { f0.y, f1.x, f1.w, f2.z };
        float bzs[4] = { f0.z, f1.y, f2.x, f2.w };
        #pragma unroll
        for (int k = 0; k < 4; ++k) {
            const int c = c0i + k;
            float bx = bxs[k], by = bys[k], bz = bzs[k];
            float m2x = -2.f*bx, m2y = -2.f*by, m2z = -2.f*bz;
            unsigned short hx = f2bf(m2x), hy = f2bf(m2y), hz = f2bf(m2z);
            unsigned short lx = f2bf(m2x - bf2f(hx));
            unsigned short ly = f2bf(m2y - bf2f(hy));
            unsigned short lz = f2bf(m2z - bf2f(hz));
            float b2 = fmaf(bx,bx, fmaf(by,by, bz*bz));
            unsigned short b2h = f2bf(b2);
            unsigned short b2l = f2bf(b2 - bf2f(b2h));
            short8 kg0 = { (short)hx,(short)hy,(short)hz,(short)hx,(short)hy,(short)hz,(short)lx,(short)ly };
            short8 kg1 = { (short)lz,(short)b2h,(short)b2l, BF16_ONE, BF16_ONE, 0,0,0 };
            char* tbase = cands + (c >> 5) * 1024 + (c & 31) * 16;
            *(short8*)(tbase)       = kg0;
            *(short8*)(tbase + 512) = kg1;
        }
    }

    // ---- A-frags from global (row = lane&31, k = (lane>>5)*8 + j) ----
    short8 af0, af1;
    const float* qb = Q + ((size_t)batch * NPTS + (size_t)qc * 512) * 3;
    #pragma unroll
    for (int qt = 0; qt < 2; ++qt) {
        const int qi = (wid * 2 + qt) * 32 + lr;    // 0..511
        float x = qb[qi*3+0], y = qb[qi*3+1], z = qb[qi*3+2];
        unsigned short hx = f2bf(x), hy = f2bf(y), hz = f2bf(z);
        unsigned short lx = f2bf(x - bf2f(hx));
        unsigned short ly = f2bf(y - bf2f(hy));
        unsigned short lz = f2bf(z - bf2f(hz));
        float a2 = fmaf(x,x, fmaf(y,y, z*z));
        unsigned short a2h = f2bf(a2);
        unsigned short a2l = f2bf(a2 - bf2f(a2h));
        short8 f;
        if (lh == 0)
            f = (short8){ (short)hx,(short)hy,(short)hz,(short)lx,(short)ly,(short)lz,(short)hx,(short)hy };
        else
            f = (short8){ (short)hz, BF16_ONE, BF16_ONE, (short)a2h,(short)a2l, 0,0,0 };
        if (qt == 0) af0 = f; else af1 = f;
    }
    __syncthreads();

    // ---- software-pipelined main loop: 32 stages of 2 tiles (R18-verified) ----
    u32x16 mnU, mnU2;
    f32x16 zero16;
    #pragma unroll
    for (int r = 0; r < 16; ++r) { mnU[r] = FMAX_BITS; mnU2[r] = FMAX_BITS; zero16[r] = 0.f; }

    const char* cp = cands + lh * 512 + lr * 16;
    short8 c0 = *(const short8*)(cp);
    short8 c1 = *(const short8*)(cp + 1024);
    short8 n0 = *(const short8*)(cp + 2048);
    short8 n1 = *(const short8*)(cp + 3072);
    cp += 4096;
    f32x16 p00 = __builtin_amdgcn_mfma_f32_32x32x16_bf16(af0, c0, zero16, 0,0,0);
    f32x16 p01 = __builtin_amdgcn_mfma_f32_32x32x16_bf16(af0, c1, zero16, 0,0,0);
    f32x16 p10 = __builtin_amdgcn_mfma_f32_32x32x16_bf16(af1, c0, zero16, 0,0,0);
    f32x16 p11 = __builtin_amdgcn_mfma_f32_32x32x16_bf16(af1, c1, zero16, 0,0,0);

    #pragma unroll 2
    for (int s = 1; s < 31; ++s) {        // stages 1..30 (tiles 2..61)
        c0 = n0; c1 = n1;
        n0 = *(const short8*)(cp);        // prefetch stage s+1
        n1 = *(const short8*)(cp + 1024);
        cp += 2048;
        f32x16 q00 = __builtin_amdgcn_mfma_f32_32x32x16_bf16(af0, c0, zero16, 0,0,0);
        f32x16 q01 = __builtin_amdgcn_mfma_f32_32x32x16_bf16(af0, c1, zero16, 0,0,0);
        f32x16 q10 = __builtin_amdgcn_mfma_f32_32x32x16_bf16(af1, c0, zero16, 0,0,0);
        f32x16 q11 = __builtin_amdgcn_mfma_f32_32x32x16_bf16(af1, c1, zero16, 0,0,0);
        #pragma unroll
        for (int r = 0; r < 16; ++r)      // fold stage s-1 (completed)
            mnU[r]  = umin2(umin2(f2u(p00[r]), f2u(p01[r])), mnU[r]);
        #pragma unroll
        for (int r = 0; r < 16; ++r)
            mnU2[r] = umin2(umin2(f2u(p10[r]), f2u(p11[r])), mnU2[r]);
        p00 = q00; p01 = q01; p10 = q10; p11 = q11;
    }
    {   // stage 31 (tiles 62,63, prefetched in n0/n1) + drain folds
        f32x16 q00 = __builtin_amdgcn_mfma_f32_32x32x16_bf16(af0, n0, zero16, 0,0,0);
        f32x16 q01 = __builtin_amdgcn_mfma_f32_32x32x16_bf16(af0, n1, zero16, 0,0,0);
        f32x16 q10 = __builtin_amdgcn_mfma_f32_32x32x16_bf16(af1, n0, zero16, 0,0,0);
        f32x16 q11 = __builtin_amdgcn_mfma_f32_32x32x16_bf16(af1, n1, zero16, 0,0,0);
        #pragma unroll
        for (int r = 0; r < 16; ++r) {
            mnU[r]  = umin2(umin2(f2u(p00[r]), f2u(p01[r])), mnU[r]);
            mnU2[r] = umin2(umin2(f2u(p10[r]), f2u(p11[r])), mnU2[r]);
        }
        #pragma unroll
        for (int r = 0; r < 16; ++r) {
            mnU[r]  = umin2(umin2(f2u(q00[r]), f2u(q01[r])), mnU[r]);
            mnU2[r] = umin2(umin2(f2u(q10[r]), f2u(q11[r])), mnU2[r]);
        }
    }

    // ---- epilogue: DPP row_ror col-reduce (R19-verified) ----
    float s = 0.f;
    #pragma unroll
    for (int r = 0; r < 16; ++r) {
        unsigned v = mnU[r];
        v = dpp_ror_umin<0x121>(v);
        v = dpp_ror_umin<0x122>(v);
        v = dpp_ror_umin<0x124>(v);
        v = dpp_ror_umin<0x128>(v);
        v = swz16_umin(v);
        s += u2f(v);
        unsigned w = mnU2[r];
        w = dpp_ror_umin<0x121>(w);
        w = dpp_ror_umin<0x122>(w);
        w = dpp_ror_umin<0x124>(w);
        w = dpp_ror_umin<0x128>(w);
        w = swz16_umin(w);
        s += u2f(w);
    }
    s += __shfl_xor(s, 32, 64);      // combine lh=0 / lh=1 query halves
    if (lane == 0) wsum[wid] = s;
    __syncthreads();
    if (tid == 0) {
        partial[blk] = ((wsum[0] + wsum[1]) + (wsum[2] + wsum[3]))
                     + ((wsum[4] + wsum[5]) + (wsum[6] + wsum[7]));
    }
}

__global__ __launch_bounds__(256) void finalize_kernel(
    const float* __restrict__ partial, const float* __restrict__ pred,
    const int* __restrict__ gt, float* __restrict__ out)
{
    __shared__ float s_ce[BATCH];
    __shared__ float wsum[4];
    const int tid = threadIdx.x;

    float v = partial[tid];          // 256 partials
    #pragma unroll
    for (int o = 32; o > 0; o >>= 1) v += __shfl_down(v, o, 64);
    const int lane = tid & 63, wid = tid >> 6;
    if (lane == 0) wsum[wid] = v;

    if (tid < BATCH) {
        const float* row = pred + tid * NUM_CLASSES;
        float mx = row[0];
        #pragma unroll
        for (int c = 1; c < NUM_CLASSES; ++c) mx = fmaxf(mx, row[c]);
        float se = 0.f;
        #pragma unroll
        for (int c = 0; c < NUM_CLASSES; ++c) se += __expf(row[c] - mx);
        const int lbl = gt[tid];
        s_ce[tid] = -(row[lbl] - mx - __logf(se));
    }
    __syncthreads();

    if (tid == 0) {
        float cd_sum = (wsum[0] + wsum[1]) + (wsum[2] + wsum[3]);
        float cd = cd_sum / (float)(BATCH * NPTS);
        float ce = 0.f;
        for (int i = 0; i < BATCH; ++i) ce += s_ce[i];
        ce /= (float)BATCH;
        out[0] = 5.f * cd + ce;
        out[1] = cd;
        out[2] = ce;
    }
}

extern "C" void kernel_launch(void* const* d_in, const int* in_sizes, int n_in,
                              void* d_out, int out_size, void* d_ws, size_t ws_size,
                              hipStream_t stream) {
    const float* inst  = (const float*)d_in[0];
    const float* model = (const float*)d_in[1];
    const float* pred  = (const float*)d_in[2];
    const int*   gt    = (const int*)d_in[3];
    float* out     = (float*)d_out;
    float* partial = (float*)d_ws;   // 256 floats

    chamfer_mfma32<<<256, THREADS, 0, stream>>>(inst, model, partial);
    finalize_kernel<<<1, 256, 0, stream>>>(partial, pred, gt, out);
}